// Round 11
// baseline (372.010 us; speedup 1.0000x reference)
//
#include <hip/hip_runtime.h>

// ---------------------------------------------------------------------------
// GIN forward, bf16 internal storage. 3x { agg = h + scatter(w*h[src]);
// h = relu(agg@W+b) }, layer3+pool fused: out[g]=pool_g(h2+agg3)@W3+cnt*b3.
// CSR by bucketed counting sort (R5). Aggregate: one node per wave,
// 4-edge-parallel gather (R6/R10: pinned at ~63us, gather-fabric-bound).
// R11: layers 1+2 fuse aggregate+MFMA GEMM in one kernel (16 waves = 16
// nodes = one MFMA row-tile; deletes the 100MB Ha round-trip), and CSR
// stream reads are non-temporal (keep the 12.8MB/pass stream out of L2 so
// H-row gathers hit more).
// ---------------------------------------------------------------------------

typedef __attribute__((ext_vector_type(8))) short short8;
typedef __attribute__((ext_vector_type(4))) float f32x4;

__device__ __forceinline__ unsigned short f2bf(float f) {
    unsigned u = __builtin_bit_cast(unsigned, f);
    u += 0x7fff + ((u >> 16) & 1);           // RNE
    return (unsigned short)(u >> 16);
}
__device__ __forceinline__ float bf2f(unsigned short s) {
    unsigned u = (unsigned)s << 16;
    return __builtin_bit_cast(float, u);
}
__device__ __forceinline__ float bflo(unsigned u) {
    return __builtin_bit_cast(float, u << 16);
}
__device__ __forceinline__ float bfhi(unsigned u) {
    return __builtin_bit_cast(float, u & 0xffff0000u);
}
__device__ __forceinline__ unsigned packbf(float a, float b) {
    return (unsigned)f2bf(a) | ((unsigned)f2bf(b) << 16);
}

#define BKT_SHIFT 8
#define BKT_NODES 256            // nodes per bucket; NB <= 512 (N < 131072)
#define PCHUNK 4096              // edges per partition block
#define SB_CAP 7168              // max edges per bucket in sort LDS

// ---- bucket-level histogram (LDS-aggregated, coalesced reads) -------------
__global__ __launch_bounds__(256) void bucket_hist(const int* __restrict__ dst,
                                                   int* __restrict__ bh, int E_) {
    __shared__ int lh[512];
    for (int i = threadIdx.x; i < 512; i += 256) lh[i] = 0;
    __syncthreads();
    for (int i = blockIdx.x * 256 + threadIdx.x; i < E_; i += gridDim.x * 256)
        atomicAdd(&lh[dst[i] >> BKT_SHIFT], 1);
    __syncthreads();
    for (int i = threadIdx.x; i < 512; i += 256)
        if (lh[i]) atomicAdd(&bh[i], lh[i]);
}

// ---- bucket scan: bstart (exclusive), gcursor init, rp[N]=E ---------------
__global__ __launch_bounds__(512) void bucket_scan(const int* __restrict__ bh,
                                                   int* __restrict__ bstart,
                                                   int* __restrict__ gcur,
                                                   int* __restrict__ rp,
                                                   int NB, int N_, int E_) {
    __shared__ int sd[512];
    const int tid = threadIdx.x;
    int v = (tid < NB) ? bh[tid] : 0;
    sd[tid] = v;
    __syncthreads();
    for (int ofs = 1; ofs < 512; ofs <<= 1) {
        int t = (tid >= ofs) ? sd[tid - ofs] : 0;
        __syncthreads();
        sd[tid] += t;
        __syncthreads();
    }
    int excl = sd[tid] - v;
    if (tid < NB) { bstart[tid] = excl; gcur[tid] = excl; }
    if (tid == NB - 1) bstart[NB] = excl + v;   // == E_
    if (tid == 0) rp[N_] = E_;
}

// ---- partition edges into bucket regions (coalesced run writes) -----------
__global__ __launch_bounds__(256) void partition_edges(const int* __restrict__ src,
                                                       const int* __restrict__ dst,
                                                       const float* __restrict__ ew,
                                                       int* __restrict__ gcur,
                                                       uint2* __restrict__ temp, int E_) {
    __shared__ int lcur[512];
    __shared__ int lexcl[512];
    __shared__ int gbase[512];
    __shared__ unsigned short bof[PCHUNK];
    __shared__ uint2 stag[PCHUNK];
    __shared__ int sd[256];
    const int tid = threadIdx.x;
    const int e0  = blockIdx.x * PCHUNK;
    const int n   = min(PCHUNK, E_ - e0);

    for (int i = tid; i < 512; i += 256) lcur[i] = 0;
    __syncthreads();
    for (int i = tid; i < n; i += 256)
        atomicAdd(&lcur[dst[e0 + i] >> BKT_SHIFT], 1);
    __syncthreads();
    const int a0 = lcur[2 * tid], a1 = lcur[2 * tid + 1];
    const int ps = a0 + a1;
    sd[tid] = ps;
    __syncthreads();
    for (int ofs = 1; ofs < 256; ofs <<= 1) {
        int t = (tid >= ofs) ? sd[tid - ofs] : 0;
        __syncthreads();
        sd[tid] += t;
        __syncthreads();
    }
    const int pexcl = sd[tid] - ps;
    __syncthreads();
    lexcl[2 * tid] = pexcl;      lexcl[2 * tid + 1] = pexcl + a0;
    lcur [2 * tid] = pexcl;      lcur [2 * tid + 1] = pexcl + a0;
    __syncthreads();
    for (int i = tid; i < n; i += 256) {
        int   s = src[e0 + i], d = dst[e0 + i];
        float wv = ew[e0 + i];
        int b = d >> BKT_SHIFT;
        int p = atomicAdd(&lcur[b], 1);
        stag[p].x = (unsigned)s | ((unsigned)(d & (BKT_NODES - 1)) << 17);
        stag[p].y = __float_as_uint(wv);
        bof[p] = (unsigned short)b;
    }
    __syncthreads();
    if (a0) gbase[2 * tid]     = atomicAdd(&gcur[2 * tid],     a0);
    if (a1) gbase[2 * tid + 1] = atomicAdd(&gcur[2 * tid + 1], a1);
    __syncthreads();
    for (int i = tid; i < n; i += 256) {
        int b = bof[i];
        temp[gbase[b] + (i - lexcl[b])] = stag[i];
    }
}

// ---- per-bucket counting sort by dst low bits; writes csr + rp ------------
__global__ __launch_bounds__(256) void sort_bucket(const uint2* __restrict__ temp,
                                                   const int* __restrict__ bstart,
                                                   uint2* __restrict__ csr,
                                                   int* __restrict__ rp, int N_) {
    __shared__ int h[256], hcur[256], sd[256];
    __shared__ uint2 outb[SB_CAP];
    const int b = blockIdx.x, tid = threadIdx.x;
    const int lo = bstart[b], hi = bstart[b + 1];
    const int L = hi - lo;
    h[tid] = 0;
    __syncthreads();
    for (int i = tid; i < L; i += 256)
        atomicAdd(&h[(temp[lo + i].x >> 17) & (BKT_NODES - 1)], 1);
    __syncthreads();
    int v = h[tid];
    sd[tid] = v;
    __syncthreads();
    for (int ofs = 1; ofs < 256; ofs <<= 1) {
        int t = (tid >= ofs) ? sd[tid - ofs] : 0;
        __syncthreads();
        sd[tid] += t;
        __syncthreads();
    }
    const int excl = sd[tid] - v;
    hcur[tid] = excl;
    const int node = b * BKT_NODES + tid;
    if (node <= N_) rp[node] = lo + excl;
    __syncthreads();
    for (int i = tid; i < L; i += 256) {
        uint2 p = temp[lo + i];
        int pos = atomicAdd(&hcur[(p.x >> 17) & (BKT_NODES - 1)], 1);
        outb[pos] = p;
    }
    __syncthreads();
    for (int i = tid; i < L; i += 256) csr[lo + i] = outb[i];
}

// ---- f32 -> bf16 row conversion (for x) -----------------------------------
__global__ __launch_bounds__(256) void convert_bf16(const float* __restrict__ in,
                                                    unsigned short* __restrict__ out, int n8) {
    int i = blockIdx.x * 256 + threadIdx.x;
    if (i >= n8) return;
    const float4* in4 = (const float4*)in;
    float4 a = in4[(size_t)i * 2], b = in4[(size_t)i * 2 + 1];
    short8 o;
    o[0] = (short)f2bf(a.x); o[1] = (short)f2bf(a.y);
    o[2] = (short)f2bf(a.z); o[3] = (short)f2bf(a.w);
    o[4] = (short)f2bf(b.x); o[5] = (short)f2bf(b.y);
    o[6] = (short)f2bf(b.z); o[7] = (short)f2bf(b.w);
    ((short8*)out)[i] = o;
}

// ---- W pack: f32 [128][128] -> bf16 fragment order [cf][kg][lane][8] ------
__global__ __launch_bounds__(256) void pack_w(const float* __restrict__ W,
                                              unsigned short* __restrict__ Wp) {
    int idx = blockIdx.x * 256 + threadIdx.x;        // 0..16383
    int j = idx & 7, lane = (idx >> 3) & 63, kg = (idx >> 9) & 3, cf = idx >> 11;
    int k = kg * 32 + ((lane >> 4) & 3) * 8 + j;
    int c = cf * 16 + (lane & 15);
    Wp[idx] = f2bf(W[k * 128 + c]);
}

// ---- per-node aggregation core (shared by both kernels) -------------------
// Wave aggregates one node into acc[8] (per-lane, 4-group split); after the
// shfl_xor reduce, qid==0 lanes hold the full row (lane qlane = bytes
// [16*qlane,16*qlane+16) as 8 f32).
__device__ __forceinline__ void agg_node(const uint4* __restrict__ H4,
                                         const int* __restrict__ rp,
                                         const uint2* __restrict__ csr,
                                         int node, int lane, int qid, int qlane,
                                         float acc[8]) {
    const int e0 = rp[node], e1 = rp[node + 1];
    for (int base = e0; base < e1; base += 64) {
        const int cnt = min(64, e1 - base);
        int   sv = 0;
        float wv = 0.f;
        if (base + lane < e1) {
            unsigned long long pv = __builtin_nontemporal_load(
                (const unsigned long long*)csr + (base + lane));
            sv = (int)((unsigned)pv & 0x1FFFF);
            wv = __builtin_bit_cast(float, (unsigned)(pv >> 32));
        }
        const int g4 = (cnt + 3) >> 2;
#pragma unroll 4
        for (int jg = 0; jg < g4; jg++) {
            int   j  = jg * 4 + qid;
            int   sj = __shfl(sv, j);
            float wj = __shfl(wv, j);      // 0 for tail slots -> no contribution
            uint4 v  = H4[(size_t)sj * 16 + qlane];
            acc[0] += wj * bflo(v.x); acc[1] += wj * bfhi(v.x);
            acc[2] += wj * bflo(v.y); acc[3] += wj * bfhi(v.y);
            acc[4] += wj * bflo(v.z); acc[5] += wj * bfhi(v.z);
            acc[6] += wj * bflo(v.w); acc[7] += wj * bfhi(v.w);
        }
    }
#pragma unroll
    for (int i = 0; i < 8; i++) {
        acc[i] += __shfl_xor(acc[i], 16);
        acc[i] += __shfl_xor(acc[i], 32);
    }
}

// ---- fused aggregate + MFMA GEMM (layers 1 & 2) ---------------------------
// 1024 threads = 16 waves = 16 nodes = one MFMA row tile. Each wave
// aggregates its node (identical structure to standalone), parks the bf16
// row in LDS (row stride 272B: 2-way bank access = free), then waves 0..7
// compute Out[16 x 128] = relu(Agg @ W + b) with 4 mfma_16x16x32 each.
__global__ __launch_bounds__(1024) void agg_gemm(const unsigned short* __restrict__ H,
                                                 const int* __restrict__ rp,
                                                 const uint2* __restrict__ csr,
                                                 const unsigned short* __restrict__ Wp,
                                                 const float* __restrict__ bias,
                                                 unsigned short* __restrict__ Out,
                                                 int n) {
    __shared__ unsigned Ag[16][68];          // 16 rows x 128 bf16 (+4 uint pad)
    const int wv   = threadIdx.x >> 6;       // 0..15 = row in tile
    const int lane = threadIdx.x & 63;
    const int qid = lane >> 4, qlane = lane & 15;
    const int node = blockIdx.x * 16 + wv;
    const uint4* H4 = (const uint4*)H;

    if (node < n) {
        uint4 self = H4[(size_t)node * 16 + qlane];
        float acc[8];
#pragma unroll
        for (int i = 0; i < 8; i++) acc[i] = 0.f;
        agg_node(H4, rp, csr, node, lane, qid, qlane, acc);
        if (qid == 0) {
            acc[0] += bflo(self.x); acc[1] += bfhi(self.x);
            acc[2] += bflo(self.y); acc[3] += bfhi(self.y);
            acc[4] += bflo(self.z); acc[5] += bfhi(self.z);
            acc[6] += bflo(self.w); acc[7] += bfhi(self.w);
            uint4 o;
            o.x = packbf(acc[0], acc[1]);
            o.y = packbf(acc[2], acc[3]);
            o.z = packbf(acc[4], acc[5]);
            o.w = packbf(acc[6], acc[7]);
            *(uint4*)&Ag[wv][qlane * 4] = o;
        }
    } else if (qid == 0) {
        uint4 z = {0u, 0u, 0u, 0u};
        *(uint4*)&Ag[wv][qlane * 4] = z;
    }
    __syncthreads();

    if (wv < 8) {                            // wave wv computes col-frag cf=wv
        const int row = lane & 15, hi = lane >> 4;
        short8 a[4];
#pragma unroll
        for (int kg = 0; kg < 4; kg++) {
            uint4 t = *(const uint4*)&Ag[row][kg * 16 + hi * 4];
            a[kg] = __builtin_bit_cast(short8, t);
        }
        const short8* Bp = (const short8*)Wp;
        f32x4 accv = {0.f, 0.f, 0.f, 0.f};
#pragma unroll
        for (int kg = 0; kg < 4; kg++) {
            short8 b = Bp[(wv * 4 + kg) * 64 + lane];
            accv = __builtin_amdgcn_mfma_f32_16x16x32_bf16(a[kg], b, accv, 0, 0, 0);
        }
        const float bvv = bias[wv * 16 + row];
        const int drow = blockIdx.x * 16 + hi * 4;
        const int dcol = wv * 16 + row;
#pragma unroll
        for (int i = 0; i < 4; i++) {
            int r = drow + i;
            if (r < n)
                Out[(size_t)r * 128 + dcol] = f2bf(fmaxf(accv[i] + bvv, 0.f));
        }
    }
}

// ---- standalone aggregation (layer 3): Out[n] = H[n] + sum w*H[src] -------
__global__ __launch_bounds__(256) void aggregate_bf16(const unsigned short* __restrict__ H,
                                                      const int* __restrict__ rp,
                                                      const uint2* __restrict__ csr,
                                                      unsigned short* __restrict__ Out, int n) {
    const int node = blockIdx.x * 4 + (threadIdx.x >> 6);
    const int lane = threadIdx.x & 63;
    if (node >= n) return;
    const int qid = lane >> 4, qlane = lane & 15;
    const uint4* H4 = (const uint4*)H;

    uint4 self = H4[(size_t)node * 16 + qlane];
    float acc[8];
#pragma unroll
    for (int i = 0; i < 8; i++) acc[i] = 0.f;
    agg_node(H4, rp, csr, node, lane, qid, qlane, acc);

    if (qid == 0) {
        acc[0] += bflo(self.x); acc[1] += bfhi(self.x);
        acc[2] += bflo(self.y); acc[3] += bfhi(self.y);
        acc[4] += bflo(self.z); acc[5] += bfhi(self.z);
        acc[6] += bflo(self.w); acc[7] += bfhi(self.w);
        uint4 o;
        o.x = packbf(acc[0], acc[1]);
        o.y = packbf(acc[2], acc[3]);
        o.z = packbf(acc[4], acc[5]);
        o.w = packbf(acc[6], acc[7]);
        ((uint4*)Out)[(size_t)node * 16 + qlane] = o;
    }
}

// ---- pooling ---------------------------------------------------------------
__global__ __launch_bounds__(256) void graph_count(const int* __restrict__ batch,
                                                   int* __restrict__ cnt, int n) {
    int t  = blockIdx.x * 256 + threadIdx.x;
    int i0 = t * 16;
    if (i0 >= n) return;
    int end = min(i0 + 16, n);
    int g = batch[i0], c = 0;
    for (int i = i0; i < end; i++) {
        int gi = batch[i];
        if (gi != g) { atomicAdd(&cnt[g], c); g = gi; c = 0; }
        c++;
    }
    atomicAdd(&cnt[g], c);
}

// P[g][k] += sum_{n in g} H[n][k]. 64-row chunk per block, 4 waves; wave w
// visits rows start+w, start+w+4, ...; run-length flush (batch sorted).
__global__ __launch_bounds__(256) void pool_nodes(const unsigned short* __restrict__ H,
                                                  const int* __restrict__ batch,
                                                  float* __restrict__ P, int n) {
    const int k2 = threadIdx.x & 63;        // feature pair
    const int wv = threadIdx.x >> 6;        // wave = row stride phase
    int r = blockIdx.x * 64 + wv;
    const int end = min(blockIdx.x * 64 + 64, n);
    if (r >= end) return;
    const unsigned* H32 = (const unsigned*)H;
    float ax = 0.f, ay = 0.f;
    int gcur = batch[r];
    for (; r < end; r += 4) {
        int g = batch[r];                    // wave-uniform scalar load
        if (g != gcur) {
            atomicAdd(&P[gcur * 128 + 2 * k2], ax);
            atomicAdd(&P[gcur * 128 + 2 * k2 + 1], ay);
            ax = ay = 0.f;
            gcur = g;
        }
        unsigned v = H32[(size_t)r * 64 + k2];
        ax += bflo(v);
        ay += bfhi(v);
    }
    atomicAdd(&P[gcur * 128 + 2 * k2], ax);
    atomicAdd(&P[gcur * 128 + 2 * k2 + 1], ay);
}

__global__ __launch_bounds__(256) void final_kernel(const float* __restrict__ P,
                                                    const float* __restrict__ W3,
                                                    const float* __restrict__ b3,
                                                    const int* __restrict__ cnt,
                                                    float* __restrict__ out, int total) {
    int idx = blockIdx.x * 256 + threadIdx.x;
    if (idx >= total) return;
    int g = idx / 40, c = idx % 40;
    float acc = (float)cnt[g] * b3[c];
    for (int kk = 0; kk < 128; kk++) acc += P[g * 128 + kk] * W3[kk * 40 + c];
    out[idx] = acc;
}

// ---------------------------------------------------------------------------
extern "C" void kernel_launch(void* const* d_in, const int* in_sizes, int n_in,
                              void* d_out, int out_size, void* d_ws, size_t ws_size,
                              hipStream_t stream) {
    const float* x     = (const float*)d_in[0];
    const int*   ei    = (const int*)d_in[1];
    const float* ew    = (const float*)d_in[2];
    const int*   batch = (const int*)d_in[3];
    const float* W1    = (const float*)d_in[4];
    const float* b1    = (const float*)d_in[5];
    const float* W2    = (const float*)d_in[6];
    const float* b2    = (const float*)d_in[7];
    const float* W3    = (const float*)d_in[8];
    const float* b3    = (const float*)d_in[9];
    float*       out   = (float*)d_out;

    const int E_ = in_sizes[2];   // edge_weight length
    const int N_ = in_sizes[3];   // batch length  (N_ < 131072 for 17-bit src pack)
    const int* srcp = ei;
    const int* dstp = ei + E_;
    const int NB = (N_ + BKT_NODES - 1) >> BKT_SHIFT;

    char*  w   = (char*)d_ws;
    size_t off = 0;
    auto take = [&](size_t bytes) -> char* {
        char* p = w + off;
        off = (off + bytes + 255) & ~(size_t)255;
        return p;
    };
    unsigned short* xb  = (unsigned short*)take((size_t)N_ * 128 * 2);
    unsigned short* Ha  = (unsigned short*)take((size_t)N_ * 128 * 2);
    unsigned short* Hb  = (unsigned short*)take((size_t)N_ * 128 * 2);
    int*   rp      = (int*)take((size_t)(N_ + 1) * 4);
    uint2* tempE   = (uint2*)take((size_t)E_ * 8);
    uint2* csr     = (uint2*)take((size_t)E_ * 8);
    int*   bh      = (int*)take(512 * 4);
    int*   bstart  = (int*)take(513 * 4);
    int*   gcur    = (int*)take(512 * 4);
    float* P       = (float*)take(64 * 128 * 4);   // P and cnt adjacent:
    int*   cnt     = (int*)take(64 * 4);           // one memset covers both
    unsigned short* W1p = (unsigned short*)take(16384 * 2);
    unsigned short* W2p = (unsigned short*)take(16384 * 2);
    (void)ws_size; (void)n_in;

    // ---- CSR build via bucketed counting sort (all writes coalesced) ----
    hipMemsetAsync(bh, 0, 512 * 4, stream);
    bucket_hist<<<1024, 256, 0, stream>>>(dstp, bh, E_);
    bucket_scan<<<1, 512, 0, stream>>>(bh, bstart, gcur, rp, NB, N_, E_);
    partition_edges<<<(E_ + PCHUNK - 1) / PCHUNK, 256, 0, stream>>>(srcp, dstp, ew,
                                                                    gcur, tempE, E_);
    sort_bucket<<<NB, 256, 0, stream>>>(tempE, bstart, csr, rp, N_);

    // bf16 conversions / weight packing
    convert_bf16<<<(N_ * 16 + 255) / 256, 256, 0, stream>>>(x, xb, N_ * 16);
    pack_w<<<64, 256, 0, stream>>>(W1, W1p);
    pack_w<<<64, 256, 0, stream>>>(W2, W2p);

    const int fgrid = (N_ + 15) / 16;
    const int agrid = (N_ + 3) / 4;
    // layer 1 (fused aggregate + GEMM): xb -> Hb
    agg_gemm<<<fgrid, 1024, 0, stream>>>(xb, rp, csr, W1p, b1, Hb, N_);
    // layer 2 (fused): Hb -> Ha
    agg_gemm<<<fgrid, 1024, 0, stream>>>(Hb, rp, csr, W2p, b2, Ha, N_);
    // layer 3 aggregate (h2 + agg3): Ha -> Hb, then pooled path
    aggregate_bf16<<<agrid, 256, 0, stream>>>(Ha, rp, csr, Hb, N_);

    hipMemsetAsync(P, 0, 64 * 128 * 4 + 64 * 4, stream);   // P + cnt (adjacent)
    graph_count<<<((N_ + 15) / 16 + 255) / 256, 256, 0, stream>>>(batch, cnt, N_);
    pool_nodes<<<(N_ + 63) / 64, 256, 0, stream>>>(Hb, batch, P, N_);
    final_kernel<<<(out_size + 255) / 256, 256, 0, stream>>>(P, W3, b3, cnt, out, out_size);
}

// Round 12
// 364.776 us; speedup vs baseline: 1.0198x; 1.0198x over previous
//
#include <hip/hip_runtime.h>

// ---------------------------------------------------------------------------
// GIN forward, bf16 internal storage. 3x { agg = h + scatter(w*h[src]);
// h = relu(agg@W+b) }, layer3+pool fused: out[g]=pool_g(h2+agg3)@W3+cnt*b3.
// CSR by bucketed counting sort (R5, coalesced writes). Aggregate: one node
// per wave, 4-edge-parallel uint4 gather (R6), nt CSR loads (R11).
// R11 lesson: agg+GEMM fusion regressed (barrier couples 16 waves, kills
// gather MLP; 800K LDS conflicts) -> keep kernels separate, independent waves.
// Aggregate FETCH 192MB ~= comm lower bound (~176MB: 8 XCDs x 25.6MB x 0.86).
// ---------------------------------------------------------------------------

typedef __attribute__((ext_vector_type(8))) short short8;
typedef __attribute__((ext_vector_type(4))) float f32x4;

__device__ __forceinline__ unsigned short f2bf(float f) {
    unsigned u = __builtin_bit_cast(unsigned, f);
    u += 0x7fff + ((u >> 16) & 1);           // RNE
    return (unsigned short)(u >> 16);
}
__device__ __forceinline__ float bflo(unsigned u) {
    return __builtin_bit_cast(float, u << 16);
}
__device__ __forceinline__ float bfhi(unsigned u) {
    return __builtin_bit_cast(float, u & 0xffff0000u);
}
__device__ __forceinline__ unsigned packbf(float a, float b) {
    return (unsigned)f2bf(a) | ((unsigned)f2bf(b) << 16);
}

#define BKT_SHIFT 8
#define BKT_NODES 256            // nodes per bucket; NB <= 512 (N < 131072)
#define PCHUNK 4096              // edges per partition block
#define SB_CAP 7168              // max edges per bucket in sort LDS

// ---- bucket-level histogram (LDS-aggregated, coalesced reads) -------------
__global__ __launch_bounds__(256) void bucket_hist(const int* __restrict__ dst,
                                                   int* __restrict__ bh, int E_) {
    __shared__ int lh[512];
    for (int i = threadIdx.x; i < 512; i += 256) lh[i] = 0;
    __syncthreads();
    for (int i = blockIdx.x * 256 + threadIdx.x; i < E_; i += gridDim.x * 256)
        atomicAdd(&lh[dst[i] >> BKT_SHIFT], 1);
    __syncthreads();
    for (int i = threadIdx.x; i < 512; i += 256)
        if (lh[i]) atomicAdd(&bh[i], lh[i]);
}

// ---- bucket scan: bstart (exclusive), gcursor init, rp[N]=E ---------------
__global__ __launch_bounds__(512) void bucket_scan(const int* __restrict__ bh,
                                                   int* __restrict__ bstart,
                                                   int* __restrict__ gcur,
                                                   int* __restrict__ rp,
                                                   int NB, int N_, int E_) {
    __shared__ int sd[512];
    const int tid = threadIdx.x;
    int v = (tid < NB) ? bh[tid] : 0;
    sd[tid] = v;
    __syncthreads();
    for (int ofs = 1; ofs < 512; ofs <<= 1) {
        int t = (tid >= ofs) ? sd[tid - ofs] : 0;
        __syncthreads();
        sd[tid] += t;
        __syncthreads();
    }
    int excl = sd[tid] - v;
    if (tid < NB) { bstart[tid] = excl; gcur[tid] = excl; }
    if (tid == NB - 1) bstart[NB] = excl + v;   // == E_
    if (tid == 0) rp[N_] = E_;
}

// ---- partition edges into bucket regions (coalesced run writes) -----------
__global__ __launch_bounds__(256) void partition_edges(const int* __restrict__ src,
                                                       const int* __restrict__ dst,
                                                       const float* __restrict__ ew,
                                                       int* __restrict__ gcur,
                                                       uint2* __restrict__ temp, int E_) {
    __shared__ int lcur[512];
    __shared__ int lexcl[512];
    __shared__ int gbase[512];
    __shared__ unsigned short bof[PCHUNK];
    __shared__ uint2 stag[PCHUNK];
    __shared__ int sd[256];
    const int tid = threadIdx.x;
    const int e0  = blockIdx.x * PCHUNK;
    const int n   = min(PCHUNK, E_ - e0);

    for (int i = tid; i < 512; i += 256) lcur[i] = 0;
    __syncthreads();
    for (int i = tid; i < n; i += 256)
        atomicAdd(&lcur[dst[e0 + i] >> BKT_SHIFT], 1);
    __syncthreads();
    const int a0 = lcur[2 * tid], a1 = lcur[2 * tid + 1];
    const int ps = a0 + a1;
    sd[tid] = ps;
    __syncthreads();
    for (int ofs = 1; ofs < 256; ofs <<= 1) {
        int t = (tid >= ofs) ? sd[tid - ofs] : 0;
        __syncthreads();
        sd[tid] += t;
        __syncthreads();
    }
    const int pexcl = sd[tid] - ps;
    __syncthreads();
    lexcl[2 * tid] = pexcl;      lexcl[2 * tid + 1] = pexcl + a0;
    lcur [2 * tid] = pexcl;      lcur [2 * tid + 1] = pexcl + a0;
    __syncthreads();
    for (int i = tid; i < n; i += 256) {
        int   s = src[e0 + i], d = dst[e0 + i];
        float wv = ew[e0 + i];
        int b = d >> BKT_SHIFT;
        int p = atomicAdd(&lcur[b], 1);
        stag[p].x = (unsigned)s | ((unsigned)(d & (BKT_NODES - 1)) << 17);
        stag[p].y = __float_as_uint(wv);
        bof[p] = (unsigned short)b;
    }
    __syncthreads();
    if (a0) gbase[2 * tid]     = atomicAdd(&gcur[2 * tid],     a0);
    if (a1) gbase[2 * tid + 1] = atomicAdd(&gcur[2 * tid + 1], a1);
    __syncthreads();
    for (int i = tid; i < n; i += 256) {
        int b = bof[i];
        temp[gbase[b] + (i - lexcl[b])] = stag[i];
    }
}

// ---- per-bucket counting sort by dst low bits; writes csr + rp ------------
__global__ __launch_bounds__(256) void sort_bucket(const uint2* __restrict__ temp,
                                                   const int* __restrict__ bstart,
                                                   uint2* __restrict__ csr,
                                                   int* __restrict__ rp, int N_) {
    __shared__ int h[256], hcur[256], sd[256];
    __shared__ uint2 outb[SB_CAP];
    const int b = blockIdx.x, tid = threadIdx.x;
    const int lo = bstart[b], hi = bstart[b + 1];
    const int L = hi - lo;
    h[tid] = 0;
    __syncthreads();
    for (int i = tid; i < L; i += 256)
        atomicAdd(&h[(temp[lo + i].x >> 17) & (BKT_NODES - 1)], 1);
    __syncthreads();
    int v = h[tid];
    sd[tid] = v;
    __syncthreads();
    for (int ofs = 1; ofs < 256; ofs <<= 1) {
        int t = (tid >= ofs) ? sd[tid - ofs] : 0;
        __syncthreads();
        sd[tid] += t;
        __syncthreads();
    }
    const int excl = sd[tid] - v;
    hcur[tid] = excl;
    const int node = b * BKT_NODES + tid;
    if (node <= N_) rp[node] = lo + excl;
    __syncthreads();
    for (int i = tid; i < L; i += 256) {
        uint2 p = temp[lo + i];
        int pos = atomicAdd(&hcur[(p.x >> 17) & (BKT_NODES - 1)], 1);
        outb[pos] = p;
    }
    __syncthreads();
    for (int i = tid; i < L; i += 256) csr[lo + i] = outb[i];
}

// ---- merged prep: x f32->bf16 conversion + W1/W2 fragment packing ----------
// blocks [0, nconv): convert; [nconv, nconv+64): pack W1; [+64,+128): pack W2.
// pack layout: [cf][kg][lane][8], elem j: k = kg*32+(lane>>4)*8+j, c = cf*16+(lane&15)
__global__ __launch_bounds__(256) void prep_kernel(const float* __restrict__ x,
                                                   unsigned short* __restrict__ xb,
                                                   const float* __restrict__ W1,
                                                   const float* __restrict__ W2,
                                                   unsigned short* __restrict__ W1p,
                                                   unsigned short* __restrict__ W2p,
                                                   int n8, int nconv) {
    int b = blockIdx.x;
    if (b < nconv) {
        int i = b * 256 + threadIdx.x;
        if (i >= n8) return;
        const float4* in4 = (const float4*)x;
        float4 a = in4[(size_t)i * 2], c = in4[(size_t)i * 2 + 1];
        short8 o;
        o[0] = (short)f2bf(a.x); o[1] = (short)f2bf(a.y);
        o[2] = (short)f2bf(a.z); o[3] = (short)f2bf(a.w);
        o[4] = (short)f2bf(c.x); o[5] = (short)f2bf(c.y);
        o[6] = (short)f2bf(c.z); o[7] = (short)f2bf(c.w);
        ((short8*)xb)[i] = o;
    } else {
        int pb = b - nconv;                      // 0..127
        const float* W = (pb < 64) ? W1 : W2;
        unsigned short* Wp = (pb < 64) ? W1p : W2p;
        int idx = (pb & 63) * 256 + threadIdx.x; // 0..16383
        int j = idx & 7, lane = (idx >> 3) & 63, kg = (idx >> 9) & 3, cf = idx >> 11;
        int k = kg * 32 + ((lane >> 4) & 3) * 8 + j;
        int c = cf * 16 + (lane & 15);
        Wp[idx] = f2bf(W[k * 128 + c]);
    }
}

// ---- aggregation (bf16 rows): Out[n] = H[n] + sum w_e * H[src_e] ----------
// One wave per node (100K independent waves — R9/R11: never couple them).
// 4 edges in parallel: 4 lane-groups of 16, each lane uint4 (16B) => 1KB per
// load instruction. nt CSR loads (stream, no reuse). shfl_xor(16/32) reduce.
__global__ __launch_bounds__(256) void aggregate_bf16(const unsigned short* __restrict__ H,
                                                      const int* __restrict__ rp,
                                                      const uint2* __restrict__ csr,
                                                      unsigned short* __restrict__ Out, int n) {
    const int node = blockIdx.x * 4 + (threadIdx.x >> 6);
    const int lane = threadIdx.x & 63;
    if (node >= n) return;
    const int qid   = lane >> 4;      // edge slot within group-of-4
    const int qlane = lane & 15;      // 16B chunk within row
    const uint4* H4 = (const uint4*)H;

    uint4 self = H4[(size_t)node * 16 + qlane];   // issued early, used at end

    float acc[8];
#pragma unroll
    for (int i = 0; i < 8; i++) acc[i] = 0.f;

    const int e0 = rp[node], e1 = rp[node + 1];
    for (int base = e0; base < e1; base += 64) {
        const int cnt = min(64, e1 - base);
        int   sv = 0;
        float wv = 0.f;
        if (base + lane < e1) {
            unsigned long long pv = __builtin_nontemporal_load(
                (const unsigned long long*)csr + (base + lane));
            sv = (int)((unsigned)pv & 0x1FFFF);
            wv = __builtin_bit_cast(float, (unsigned)(pv >> 32));
        }
        const int g4 = (cnt + 3) >> 2;
#pragma unroll 4
        for (int jg = 0; jg < g4; jg++) {
            int   j  = jg * 4 + qid;
            int   sj = __shfl(sv, j);
            float wj = __shfl(wv, j);      // 0 for tail slots -> no contribution
            uint4 v  = H4[(size_t)sj * 16 + qlane];
            acc[0] += wj * bflo(v.x); acc[1] += wj * bfhi(v.x);
            acc[2] += wj * bflo(v.y); acc[3] += wj * bfhi(v.y);
            acc[4] += wj * bflo(v.z); acc[5] += wj * bfhi(v.z);
            acc[6] += wj * bflo(v.w); acc[7] += wj * bfhi(v.w);
        }
    }

#pragma unroll
    for (int i = 0; i < 8; i++) {
        acc[i] += __shfl_xor(acc[i], 16);
        acc[i] += __shfl_xor(acc[i], 32);
    }

    if (qid == 0) {
        acc[0] += bflo(self.x); acc[1] += bfhi(self.x);
        acc[2] += bflo(self.y); acc[3] += bfhi(self.y);
        acc[4] += bflo(self.z); acc[5] += bfhi(self.z);
        acc[6] += bflo(self.w); acc[7] += bfhi(self.w);
        uint4 o;
        o.x = packbf(acc[0], acc[1]);
        o.y = packbf(acc[2], acc[3]);
        o.z = packbf(acc[4], acc[5]);
        o.w = packbf(acc[6], acc[7]);
        ((uint4*)Out)[(size_t)node * 16 + qlane] = o;
    }
}

// ---- MFMA GEMM: Out[N,128] = relu(A[N,128] @ W + b), bf16 in/out ----------
__global__ __launch_bounds__(256) void gemm_mfma_bias_relu(const unsigned short* __restrict__ A,
                                                           const unsigned short* __restrict__ Wp,
                                                           const float* __restrict__ bias,
                                                           unsigned short* __restrict__ Out,
                                                           int nrows) {
    const int wave = threadIdx.x >> 6;
    const int lane = threadIdx.x & 63;
    const int rbase = blockIdx.x * 64 + wave * 16;
    const int arow = rbase + (lane & 15);
    const int arow_c = min(arow, nrows - 1);

    const short8* Arow = (const short8*)(A + (size_t)arow_c * 128);
    short8 a[4];
#pragma unroll
    for (int kg = 0; kg < 4; kg++) a[kg] = Arow[kg * 4 + (lane >> 4)];

    const short8* Bp = (const short8*)Wp;
    const int drow = rbase + ((lane >> 4) << 2);
    const int dcol = lane & 15;
#pragma unroll
    for (int cf = 0; cf < 8; cf++) {
        f32x4 acc = {0.f, 0.f, 0.f, 0.f};
#pragma unroll
        for (int kg = 0; kg < 4; kg++) {
            short8 b = Bp[(cf * 4 + kg) * 64 + lane];
            acc = __builtin_amdgcn_mfma_f32_16x16x32_bf16(a[kg], b, acc, 0, 0, 0);
        }
        float bv = bias[cf * 16 + dcol];
#pragma unroll
        for (int i = 0; i < 4; i++) {
            int r = drow + i;
            if (r < nrows) {
                float v = fmaxf(acc[i] + bv, 0.f);
                Out[(size_t)r * 128 + cf * 16 + dcol] = f2bf(v);
            }
        }
    }
}

// ---- pooling ---------------------------------------------------------------
__global__ __launch_bounds__(256) void graph_count(const int* __restrict__ batch,
                                                   int* __restrict__ cnt, int n) {
    int t  = blockIdx.x * 256 + threadIdx.x;
    int i0 = t * 16;
    if (i0 >= n) return;
    int end = min(i0 + 16, n);
    int g = batch[i0], c = 0;
    for (int i = i0; i < end; i++) {
        int gi = batch[i];
        if (gi != g) { atomicAdd(&cnt[g], c); g = gi; c = 0; }
        c++;
    }
    atomicAdd(&cnt[g], c);
}

// P[g][k] += sum_{n in g} H[n][k]. 64-row chunk per block, 4 waves; wave w
// visits rows start+w, start+w+4, ...; run-length flush (batch sorted).
__global__ __launch_bounds__(256) void pool_nodes(const unsigned short* __restrict__ H,
                                                  const int* __restrict__ batch,
                                                  float* __restrict__ P, int n) {
    const int k2 = threadIdx.x & 63;        // feature pair
    const int wv = threadIdx.x >> 6;        // wave = row stride phase
    int r = blockIdx.x * 64 + wv;
    const int end = min(blockIdx.x * 64 + 64, n);
    if (r >= end) return;
    const unsigned* H32 = (const unsigned*)H;
    float ax = 0.f, ay = 0.f;
    int gcur = batch[r];
    for (; r < end; r += 4) {
        int g = batch[r];                    // wave-uniform scalar load
        if (g != gcur) {
            atomicAdd(&P[gcur * 128 + 2 * k2], ax);
            atomicAdd(&P[gcur * 128 + 2 * k2 + 1], ay);
            ax = ay = 0.f;
            gcur = g;
        }
        unsigned v = H32[(size_t)r * 64 + k2];
        ax += bflo(v);
        ay += bfhi(v);
    }
    atomicAdd(&P[gcur * 128 + 2 * k2], ax);
    atomicAdd(&P[gcur * 128 + 2 * k2 + 1], ay);
}

__global__ __launch_bounds__(256) void final_kernel(const float* __restrict__ P,
                                                    const float* __restrict__ W3,
                                                    const float* __restrict__ b3,
                                                    const int* __restrict__ cnt,
                                                    float* __restrict__ out, int total) {
    int idx = blockIdx.x * 256 + threadIdx.x;
    if (idx >= total) return;
    int g = idx / 40, c = idx % 40;
    float acc = (float)cnt[g] * b3[c];
    for (int kk = 0; kk < 128; kk++) acc += P[g * 128 + kk] * W3[kk * 40 + c];
    out[idx] = acc;
}

// ---------------------------------------------------------------------------
extern "C" void kernel_launch(void* const* d_in, const int* in_sizes, int n_in,
                              void* d_out, int out_size, void* d_ws, size_t ws_size,
                              hipStream_t stream) {
    const float* x     = (const float*)d_in[0];
    const int*   ei    = (const int*)d_in[1];
    const float* ew    = (const float*)d_in[2];
    const int*   batch = (const int*)d_in[3];
    const float* W1    = (const float*)d_in[4];
    const float* b1    = (const float*)d_in[5];
    const float* W2    = (const float*)d_in[6];
    const float* b2    = (const float*)d_in[7];
    const float* W3    = (const float*)d_in[8];
    const float* b3    = (const float*)d_in[9];
    float*       out   = (float*)d_out;

    const int E_ = in_sizes[2];   // edge_weight length
    const int N_ = in_sizes[3];   // batch length  (N_ < 131072 for 17-bit src pack)
    const int* srcp = ei;
    const int* dstp = ei + E_;
    const int NB = (N_ + BKT_NODES - 1) >> BKT_SHIFT;

    char*  w   = (char*)d_ws;
    size_t off = 0;
    auto take = [&](size_t bytes) -> char* {
        char* p = w + off;
        off = (off + bytes + 255) & ~(size_t)255;
        return p;
    };
    unsigned short* xb  = (unsigned short*)take((size_t)N_ * 128 * 2);
    unsigned short* Ha  = (unsigned short*)take((size_t)N_ * 128 * 2);
    unsigned short* Hb  = (unsigned short*)take((size_t)N_ * 128 * 2);
    int*   rp      = (int*)take((size_t)(N_ + 1) * 4);
    uint2* tempE   = (uint2*)take((size_t)E_ * 8);
    uint2* csr     = (uint2*)take((size_t)E_ * 8);
    int*   bh      = (int*)take(512 * 4);
    int*   bstart  = (int*)take(513 * 4);
    int*   gcur    = (int*)take(512 * 4);
    float* P       = (float*)take(64 * 128 * 4);   // P and cnt adjacent:
    int*   cnt     = (int*)take(64 * 4);           // one memset covers both
    unsigned short* W1p = (unsigned short*)take(16384 * 2);
    unsigned short* W2p = (unsigned short*)take(16384 * 2);
    (void)ws_size; (void)n_in;

    // up-front memsets + graph_count (independent of the layer pipeline)
    hipMemsetAsync(bh, 0, 512 * 4, stream);
    hipMemsetAsync(P, 0, 64 * 128 * 4 + 64 * 4, stream);   // P + cnt (adjacent)
    graph_count<<<((N_ + 15) / 16 + 255) / 256, 256, 0, stream>>>(batch, cnt, N_);

    // ---- CSR build via bucketed counting sort (all writes coalesced) ----
    bucket_hist<<<1024, 256, 0, stream>>>(dstp, bh, E_);
    bucket_scan<<<1, 512, 0, stream>>>(bh, bstart, gcur, rp, NB, N_, E_);
    partition_edges<<<(E_ + PCHUNK - 1) / PCHUNK, 256, 0, stream>>>(srcp, dstp, ew,
                                                                    gcur, tempE, E_);
    sort_bucket<<<NB, 256, 0, stream>>>(tempE, bstart, csr, rp, N_);

    // merged prep: bf16 conversion of x + W1/W2 packing (one launch)
    const int nconv = (N_ * 16 + 255) / 256;       // N*128/8 elems, 256/blk
    prep_kernel<<<nconv + 128, 256, 0, stream>>>(x, xb, W1, W2, W1p, W2p,
                                                 N_ * 16, nconv);

    const int agrid = (N_ + 3) / 4;
    const int ggrid = (N_ + 63) / 64;
    // layer 1
    aggregate_bf16<<<agrid, 256, 0, stream>>>(xb, rp, csr, Ha, N_);
    gemm_mfma_bias_relu<<<ggrid, 256, 0, stream>>>(Ha, W1p, b1, Hb, N_);
    // layer 2
    aggregate_bf16<<<agrid, 256, 0, stream>>>(Hb, rp, csr, Ha, N_);
    gemm_mfma_bias_relu<<<ggrid, 256, 0, stream>>>(Ha, W2p, b2, Hb, N_);
    // layer 3 aggregate (h2 + agg3): Hb -> Ha, then pooled path
    aggregate_bf16<<<agrid, 256, 0, stream>>>(Hb, rp, csr, Ha, N_);

    pool_nodes<<<(N_ + 63) / 64, 256, 0, stream>>>(Ha, batch, P, N_);
    final_kernel<<<(out_size + 255) / 256, 256, 0, stream>>>(P, W3, b3, cnt, out, out_size);
}

// Round 13
// 360.540 us; speedup vs baseline: 1.0318x; 1.0117x over previous
//
#include <hip/hip_runtime.h>

// ---------------------------------------------------------------------------
// GIN forward, bf16 internal storage. 3x { agg = h + scatter(w*h[src]);
// h = relu(agg@W+b) }, layer3+pool fused: out[g]=pool_g(h2+agg3)@W3+cnt*b3.
// CSR by bucketed counting sort (R5, coalesced writes). Aggregate: one node
// per wave, 4-edge-parallel uint4 gather (R6), nt CSR loads (R11).
// Structure lessons: R9/R11 - never couple gather waves (serial nodes or
// barriers kill MLP). R12 - aggregate FETCH 192MB ~= comm floor (~176MB).
// R13: graph_count folded into pool_nodes; sort_bucket LDS 57->43KB (3/CU).
// ---------------------------------------------------------------------------

typedef __attribute__((ext_vector_type(8))) short short8;
typedef __attribute__((ext_vector_type(4))) float f32x4;

__device__ __forceinline__ unsigned short f2bf(float f) {
    unsigned u = __builtin_bit_cast(unsigned, f);
    u += 0x7fff + ((u >> 16) & 1);           // RNE
    return (unsigned short)(u >> 16);
}
__device__ __forceinline__ float bflo(unsigned u) {
    return __builtin_bit_cast(float, u << 16);
}
__device__ __forceinline__ float bfhi(unsigned u) {
    return __builtin_bit_cast(float, u & 0xffff0000u);
}
__device__ __forceinline__ unsigned packbf(float a, float b) {
    return (unsigned)f2bf(a) | ((unsigned)f2bf(b) << 16);
}

#define BKT_SHIFT 8
#define BKT_NODES 256            // nodes per bucket; NB <= 512 (N < 131072)
#define PCHUNK 4096              // edges per partition block
#define SB_CAP 5376              // max edges/bucket in sort LDS (mean 4096 + 20 sigma)

// ---- bucket-level histogram (LDS-aggregated, coalesced reads) -------------
__global__ __launch_bounds__(256) void bucket_hist(const int* __restrict__ dst,
                                                   int* __restrict__ bh, int E_) {
    __shared__ int lh[512];
    for (int i = threadIdx.x; i < 512; i += 256) lh[i] = 0;
    __syncthreads();
    for (int i = blockIdx.x * 256 + threadIdx.x; i < E_; i += gridDim.x * 256)
        atomicAdd(&lh[dst[i] >> BKT_SHIFT], 1);
    __syncthreads();
    for (int i = threadIdx.x; i < 512; i += 256)
        if (lh[i]) atomicAdd(&bh[i], lh[i]);
}

// ---- bucket scan: bstart (exclusive), gcursor init, rp[N]=E ---------------
__global__ __launch_bounds__(512) void bucket_scan(const int* __restrict__ bh,
                                                   int* __restrict__ bstart,
                                                   int* __restrict__ gcur,
                                                   int* __restrict__ rp,
                                                   int NB, int N_, int E_) {
    __shared__ int sd[512];
    const int tid = threadIdx.x;
    int v = (tid < NB) ? bh[tid] : 0;
    sd[tid] = v;
    __syncthreads();
    for (int ofs = 1; ofs < 512; ofs <<= 1) {
        int t = (tid >= ofs) ? sd[tid - ofs] : 0;
        __syncthreads();
        sd[tid] += t;
        __syncthreads();
    }
    int excl = sd[tid] - v;
    if (tid < NB) { bstart[tid] = excl; gcur[tid] = excl; }
    if (tid == NB - 1) bstart[NB] = excl + v;   // == E_
    if (tid == 0) rp[N_] = E_;
}

// ---- partition edges into bucket regions (coalesced run writes) -----------
__global__ __launch_bounds__(256) void partition_edges(const int* __restrict__ src,
                                                       const int* __restrict__ dst,
                                                       const float* __restrict__ ew,
                                                       int* __restrict__ gcur,
                                                       uint2* __restrict__ temp, int E_) {
    __shared__ int lcur[512];
    __shared__ int lexcl[512];
    __shared__ int gbase[512];
    __shared__ unsigned short bof[PCHUNK];
    __shared__ uint2 stag[PCHUNK];
    __shared__ int sd[256];
    const int tid = threadIdx.x;
    const int e0  = blockIdx.x * PCHUNK;
    const int n   = min(PCHUNK, E_ - e0);

    for (int i = tid; i < 512; i += 256) lcur[i] = 0;
    __syncthreads();
    for (int i = tid; i < n; i += 256)
        atomicAdd(&lcur[dst[e0 + i] >> BKT_SHIFT], 1);
    __syncthreads();
    const int a0 = lcur[2 * tid], a1 = lcur[2 * tid + 1];
    const int ps = a0 + a1;
    sd[tid] = ps;
    __syncthreads();
    for (int ofs = 1; ofs < 256; ofs <<= 1) {
        int t = (tid >= ofs) ? sd[tid - ofs] : 0;
        __syncthreads();
        sd[tid] += t;
        __syncthreads();
    }
    const int pexcl = sd[tid] - ps;
    __syncthreads();
    lexcl[2 * tid] = pexcl;      lexcl[2 * tid + 1] = pexcl + a0;
    lcur [2 * tid] = pexcl;      lcur [2 * tid + 1] = pexcl + a0;
    __syncthreads();
    for (int i = tid; i < n; i += 256) {
        int   s = src[e0 + i], d = dst[e0 + i];
        float wv = ew[e0 + i];
        int b = d >> BKT_SHIFT;
        int p = atomicAdd(&lcur[b], 1);
        stag[p].x = (unsigned)s | ((unsigned)(d & (BKT_NODES - 1)) << 17);
        stag[p].y = __float_as_uint(wv);
        bof[p] = (unsigned short)b;
    }
    __syncthreads();
    if (a0) gbase[2 * tid]     = atomicAdd(&gcur[2 * tid],     a0);
    if (a1) gbase[2 * tid + 1] = atomicAdd(&gcur[2 * tid + 1], a1);
    __syncthreads();
    for (int i = tid; i < n; i += 256) {
        int b = bof[i];
        temp[gbase[b] + (i - lexcl[b])] = stag[i];
    }
}

// ---- per-bucket counting sort by dst low bits; writes csr + rp ------------
__global__ __launch_bounds__(256) void sort_bucket(const uint2* __restrict__ temp,
                                                   const int* __restrict__ bstart,
                                                   uint2* __restrict__ csr,
                                                   int* __restrict__ rp, int N_) {
    __shared__ int h[256], hcur[256], sd[256];
    __shared__ uint2 outb[SB_CAP];
    const int b = blockIdx.x, tid = threadIdx.x;
    const int lo = bstart[b], hi = bstart[b + 1];
    const int L = hi - lo;
    h[tid] = 0;
    __syncthreads();
    for (int i = tid; i < L; i += 256)
        atomicAdd(&h[(temp[lo + i].x >> 17) & (BKT_NODES - 1)], 1);
    __syncthreads();
    int v = h[tid];
    sd[tid] = v;
    __syncthreads();
    for (int ofs = 1; ofs < 256; ofs <<= 1) {
        int t = (tid >= ofs) ? sd[tid - ofs] : 0;
        __syncthreads();
        sd[tid] += t;
        __syncthreads();
    }
    const int excl = sd[tid] - v;
    hcur[tid] = excl;
    const int node = b * BKT_NODES + tid;
    if (node <= N_) rp[node] = lo + excl;
    __syncthreads();
    for (int i = tid; i < L; i += 256) {
        uint2 p = temp[lo + i];
        int pos = atomicAdd(&hcur[(p.x >> 17) & (BKT_NODES - 1)], 1);
        outb[pos] = p;
    }
    __syncthreads();
    for (int i = tid; i < L; i += 256) csr[lo + i] = outb[i];
}

// ---- merged prep: x f32->bf16 conversion + W1/W2 fragment packing ----------
__global__ __launch_bounds__(256) void prep_kernel(const float* __restrict__ x,
                                                   unsigned short* __restrict__ xb,
                                                   const float* __restrict__ W1,
                                                   const float* __restrict__ W2,
                                                   unsigned short* __restrict__ W1p,
                                                   unsigned short* __restrict__ W2p,
                                                   int n8, int nconv) {
    int b = blockIdx.x;
    if (b < nconv) {
        int i = b * 256 + threadIdx.x;
        if (i >= n8) return;
        const float4* in4 = (const float4*)x;
        float4 a = in4[(size_t)i * 2], c = in4[(size_t)i * 2 + 1];
        short8 o;
        o[0] = (short)f2bf(a.x); o[1] = (short)f2bf(a.y);
        o[2] = (short)f2bf(a.z); o[3] = (short)f2bf(a.w);
        o[4] = (short)f2bf(c.x); o[5] = (short)f2bf(c.y);
        o[6] = (short)f2bf(c.z); o[7] = (short)f2bf(c.w);
        ((short8*)xb)[i] = o;
    } else {
        int pb = b - nconv;                      // 0..127
        const float* W = (pb < 64) ? W1 : W2;
        unsigned short* Wp = (pb < 64) ? W1p : W2p;
        int idx = (pb & 63) * 256 + threadIdx.x; // 0..16383
        int j = idx & 7, lane = (idx >> 3) & 63, kg = (idx >> 9) & 3, cf = idx >> 11;
        int k = kg * 32 + ((lane >> 4) & 3) * 8 + j;
        int c = cf * 16 + (lane & 15);
        Wp[idx] = f2bf(W[k * 128 + c]);
    }
}

// ---- aggregation (bf16 rows): Out[n] = H[n] + sum w_e * H[src_e] ----------
// One wave per node (100K independent waves). 4 edges in parallel: 4 lane-
// groups of 16, each lane uint4 (16B) => 1KB per load instruction.
__global__ __launch_bounds__(256) void aggregate_bf16(const unsigned short* __restrict__ H,
                                                      const int* __restrict__ rp,
                                                      const uint2* __restrict__ csr,
                                                      unsigned short* __restrict__ Out, int n) {
    const int node = blockIdx.x * 4 + (threadIdx.x >> 6);
    const int lane = threadIdx.x & 63;
    if (node >= n) return;
    const int qid   = lane >> 4;      // edge slot within group-of-4
    const int qlane = lane & 15;      // 16B chunk within row
    const uint4* H4 = (const uint4*)H;

    uint4 self = H4[(size_t)node * 16 + qlane];   // issued early, used at end

    float acc[8];
#pragma unroll
    for (int i = 0; i < 8; i++) acc[i] = 0.f;

    const int e0 = rp[node], e1 = rp[node + 1];
    for (int base = e0; base < e1; base += 64) {
        const int cnt = min(64, e1 - base);
        int   sv = 0;
        float wv = 0.f;
        if (base + lane < e1) {
            unsigned long long pv = __builtin_nontemporal_load(
                (const unsigned long long*)csr + (base + lane));
            sv = (int)((unsigned)pv & 0x1FFFF);
            wv = __builtin_bit_cast(float, (unsigned)(pv >> 32));
        }
        const int g4 = (cnt + 3) >> 2;
#pragma unroll 4
        for (int jg = 0; jg < g4; jg++) {
            int   j  = jg * 4 + qid;
            int   sj = __shfl(sv, j);
            float wj = __shfl(wv, j);      // 0 for tail slots -> no contribution
            uint4 v  = H4[(size_t)sj * 16 + qlane];
            acc[0] += wj * bflo(v.x); acc[1] += wj * bfhi(v.x);
            acc[2] += wj * bflo(v.y); acc[3] += wj * bfhi(v.y);
            acc[4] += wj * bflo(v.z); acc[5] += wj * bfhi(v.z);
            acc[6] += wj * bflo(v.w); acc[7] += wj * bfhi(v.w);
        }
    }

#pragma unroll
    for (int i = 0; i < 8; i++) {
        acc[i] += __shfl_xor(acc[i], 16);
        acc[i] += __shfl_xor(acc[i], 32);
    }

    if (qid == 0) {
        acc[0] += bflo(self.x); acc[1] += bfhi(self.x);
        acc[2] += bflo(self.y); acc[3] += bfhi(self.y);
        acc[4] += bflo(self.z); acc[5] += bfhi(self.z);
        acc[6] += bflo(self.w); acc[7] += bfhi(self.w);
        uint4 o;
        o.x = packbf(acc[0], acc[1]);
        o.y = packbf(acc[2], acc[3]);
        o.z = packbf(acc[4], acc[5]);
        o.w = packbf(acc[6], acc[7]);
        ((uint4*)Out)[(size_t)node * 16 + qlane] = o;
    }
}

// ---- MFMA GEMM: Out[N,128] = relu(A[N,128] @ W + b), bf16 in/out ----------
__global__ __launch_bounds__(256) void gemm_mfma_bias_relu(const unsigned short* __restrict__ A,
                                                           const unsigned short* __restrict__ Wp,
                                                           const float* __restrict__ bias,
                                                           unsigned short* __restrict__ Out,
                                                           int nrows) {
    const int wave = threadIdx.x >> 6;
    const int lane = threadIdx.x & 63;
    const int rbase = blockIdx.x * 64 + wave * 16;
    const int arow = rbase + (lane & 15);
    const int arow_c = min(arow, nrows - 1);

    const short8* Arow = (const short8*)(A + (size_t)arow_c * 128);
    short8 a[4];
#pragma unroll
    for (int kg = 0; kg < 4; kg++) a[kg] = Arow[kg * 4 + (lane >> 4)];

    const short8* Bp = (const short8*)Wp;
    const int drow = rbase + ((lane >> 4) << 2);
    const int dcol = lane & 15;
#pragma unroll
    for (int cf = 0; cf < 8; cf++) {
        f32x4 acc = {0.f, 0.f, 0.f, 0.f};
#pragma unroll
        for (int kg = 0; kg < 4; kg++) {
            short8 b = Bp[(cf * 4 + kg) * 64 + lane];
            acc = __builtin_amdgcn_mfma_f32_16x16x32_bf16(a[kg], b, acc, 0, 0, 0);
        }
        float bv = bias[cf * 16 + dcol];
#pragma unroll
        for (int i = 0; i < 4; i++) {
            int r = drow + i;
            if (r < nrows) {
                float v = fmaxf(acc[i] + bv, 0.f);
                Out[(size_t)r * 128 + cf * 16 + dcol] = f2bf(v);
            }
        }
    }
}

// ---- pooling: P[g][k] += sum_{n in g} H[n][k], cnt[g] += |g| ---------------
// 64-row chunk per block, 4 waves; wave w visits rows start+w, +4, ...
// (monotone under sorted batch -> exact run-length flush). Lane owns a
// feature pair; lane 0 of each wave also accumulates the node count (R13:
// replaces the separate graph_count kernel).
__global__ __launch_bounds__(256) void pool_nodes(const unsigned short* __restrict__ H,
                                                  const int* __restrict__ batch,
                                                  float* __restrict__ P,
                                                  int* __restrict__ cnt, int n) {
    const int k2 = threadIdx.x & 63;        // feature pair
    const int wv = threadIdx.x >> 6;        // wave = row stride phase
    int r = blockIdx.x * 64 + wv;
    const int end = min(blockIdx.x * 64 + 64, n);
    if (r >= end) return;
    const unsigned* H32 = (const unsigned*)H;
    float ax = 0.f, ay = 0.f;
    int runc = 0;
    int gcur = batch[r];
    for (; r < end; r += 4) {
        int g = batch[r];                    // wave-uniform scalar load
        if (g != gcur) {
            atomicAdd(&P[gcur * 128 + 2 * k2], ax);
            atomicAdd(&P[gcur * 128 + 2 * k2 + 1], ay);
            if (k2 == 0) atomicAdd(&cnt[gcur], runc);
            ax = ay = 0.f;
            runc = 0;
            gcur = g;
        }
        unsigned v = H32[(size_t)r * 64 + k2];
        ax += bflo(v);
        ay += bfhi(v);
        runc++;
    }
    atomicAdd(&P[gcur * 128 + 2 * k2], ax);
    atomicAdd(&P[gcur * 128 + 2 * k2 + 1], ay);
    if (k2 == 0) atomicAdd(&cnt[gcur], runc);
}

__global__ __launch_bounds__(256) void final_kernel(const float* __restrict__ P,
                                                    const float* __restrict__ W3,
                                                    const float* __restrict__ b3,
                                                    const int* __restrict__ cnt,
                                                    float* __restrict__ out, int total) {
    int idx = blockIdx.x * 256 + threadIdx.x;
    if (idx >= total) return;
    int g = idx / 40, c = idx % 40;
    float acc = (float)cnt[g] * b3[c];
    for (int kk = 0; kk < 128; kk++) acc += P[g * 128 + kk] * W3[kk * 40 + c];
    out[idx] = acc;
}

// ---------------------------------------------------------------------------
extern "C" void kernel_launch(void* const* d_in, const int* in_sizes, int n_in,
                              void* d_out, int out_size, void* d_ws, size_t ws_size,
                              hipStream_t stream) {
    const float* x     = (const float*)d_in[0];
    const int*   ei    = (const int*)d_in[1];
    const float* ew    = (const float*)d_in[2];
    const int*   batch = (const int*)d_in[3];
    const float* W1    = (const float*)d_in[4];
    const float* b1    = (const float*)d_in[5];
    const float* W2    = (const float*)d_in[6];
    const float* b2    = (const float*)d_in[7];
    const float* W3    = (const float*)d_in[8];
    const float* b3    = (const float*)d_in[9];
    float*       out   = (float*)d_out;

    const int E_ = in_sizes[2];   // edge_weight length
    const int N_ = in_sizes[3];   // batch length  (N_ < 131072 for 17-bit src pack)
    const int* srcp = ei;
    const int* dstp = ei + E_;
    const int NB = (N_ + BKT_NODES - 1) >> BKT_SHIFT;

    char*  w   = (char*)d_ws;
    size_t off = 0;
    auto take = [&](size_t bytes) -> char* {
        char* p = w + off;
        off = (off + bytes + 255) & ~(size_t)255;
        return p;
    };
    unsigned short* xb  = (unsigned short*)take((size_t)N_ * 128 * 2);
    unsigned short* Ha  = (unsigned short*)take((size_t)N_ * 128 * 2);
    unsigned short* Hb  = (unsigned short*)take((size_t)N_ * 128 * 2);
    int*   rp      = (int*)take((size_t)(N_ + 1) * 4);
    uint2* tempE   = (uint2*)take((size_t)E_ * 8);
    uint2* csr     = (uint2*)take((size_t)E_ * 8);
    int*   bh      = (int*)take(512 * 4);
    int*   bstart  = (int*)take(513 * 4);
    int*   gcur    = (int*)take(512 * 4);
    float* P       = (float*)take(64 * 128 * 4);   // P and cnt adjacent:
    int*   cnt     = (int*)take(64 * 4);           // one memset covers both
    unsigned short* W1p = (unsigned short*)take(16384 * 2);
    unsigned short* W2p = (unsigned short*)take(16384 * 2);
    (void)ws_size; (void)n_in;

    // up-front memsets (independent of the layer pipeline)
    hipMemsetAsync(bh, 0, 512 * 4, stream);
    hipMemsetAsync(P, 0, 64 * 128 * 4 + 64 * 4, stream);   // P + cnt (adjacent)

    // ---- CSR build via bucketed counting sort (all writes coalesced) ----
    bucket_hist<<<1024, 256, 0, stream>>>(dstp, bh, E_);
    bucket_scan<<<1, 512, 0, stream>>>(bh, bstart, gcur, rp, NB, N_, E_);
    partition_edges<<<(E_ + PCHUNK - 1) / PCHUNK, 256, 0, stream>>>(srcp, dstp, ew,
                                                                    gcur, tempE, E_);
    sort_bucket<<<NB, 256, 0, stream>>>(tempE, bstart, csr, rp, N_);

    // merged prep: bf16 conversion of x + W1/W2 packing (one launch)
    const int nconv = (N_ * 16 + 255) / 256;       // N*128/8 elems, 256/blk
    prep_kernel<<<nconv + 128, 256, 0, stream>>>(x, xb, W1, W2, W1p, W2p,
                                                 N_ * 16, nconv);

    const int agrid = (N_ + 3) / 4;
    const int ggrid = (N_ + 63) / 64;
    // layer 1
    aggregate_bf16<<<agrid, 256, 0, stream>>>(xb, rp, csr, Ha, N_);
    gemm_mfma_bias_relu<<<ggrid, 256, 0, stream>>>(Ha, W1p, b1, Hb, N_);
    // layer 2
    aggregate_bf16<<<agrid, 256, 0, stream>>>(Hb, rp, csr, Ha, N_);
    gemm_mfma_bias_relu<<<ggrid, 256, 0, stream>>>(Ha, W2p, b2, Hb, N_);
    // layer 3 aggregate (h2 + agg3): Hb -> Ha, then pooled path
    aggregate_bf16<<<agrid, 256, 0, stream>>>(Hb, rp, csr, Ha, N_);

    pool_nodes<<<(N_ + 63) / 64, 256, 0, stream>>>(Ha, batch, P, cnt, N_);
    final_kernel<<<(out_size + 255) / 256, 256, 0, stream>>>(P, W3, b3, cnt, out, out_size);
}